// Round 4
// baseline (1509.234 us; speedup 1.0000x reference)
//
#include <hip/hip_runtime.h>
#include <math.h>

#define N_NODES 100000
#define NFEAT 256
#define D1 64          // HEADS*NHID
#define HEADS 8
#define NHID 8
#define NCLASS 32
#define NUM_EDGES 1600000
#define E_TOT 1700000  // + self loops
#define NEG_SLOPE 0.2f

// dst-bucketing: 256 nodes per bucket
#define BSHIFT 8
#define NBUCK 391            // ceil(100000/256)
#define BCAP 5120            // mean edges/bucket = 4352, std ~64; +12 sigma headroom
#define BIN_EPB 4096         // edges per bin block
#define BIN_EPT 16           // per thread

// ---- workspace layout (float offsets); ws >= 74.8 MB proven in round 1 ----
#define OFF_H1    0            // 6,400,000 ; reused: h2=[0,3.2M), out2=[3.2M,6.4M)
#define OFF_OUT1  6400000      // 6,400,000
#define OFF_ALS1  12800000     // 800,000
#define OFF_ALD1  13600000     // 800,000
#define OFF_ALS2  14400000     // 100,000
#define OFF_ALD2  14500000     // 100,000
#define OFF_BCUR  14600000     // 391 ints (pad 1024)
#define OFF_BIN   14601024     // 391*5120 int2 = 4,003,840 ints -> ends 18,604,864 (74.4 MB)

__device__ __forceinline__ float lrelu(float x) { return x >= 0.f ? x : NEG_SLOPE * x; }

__device__ __forceinline__ void edge_src_dst(const int* __restrict__ ei, int e, int& src, int& dst) {
    if (e < NUM_EDGES) { src = ei[e]; dst = ei[NUM_EDGES + e]; }
    else { src = e - NUM_EDGES; dst = e - NUM_EDGES; }
}

// ---------------- K1: h1 = x @ W1, fused per-(node,head) attention logit dots ----------------
__global__ __launch_bounds__(256) void gemm1_kernel(const float* __restrict__ x,
                                                    const float* __restrict__ W1,
                                                    const float* __restrict__ a_src,
                                                    const float* __restrict__ a_dst,
                                                    float* __restrict__ h1,
                                                    float* __restrict__ als,
                                                    float* __restrict__ ald) {
    __shared__ float wl[NFEAT * D1];   // 64 KB: whole W1
    __shared__ float xs[64][20];
    const int tid = threadIdx.x;
    for (int i = tid * 4; i < NFEAT * D1; i += 256 * 4)
        *(float4*)&wl[i] = *(const float4*)&W1[i];

    const int r0 = blockIdx.x * 64;
    const int rl = tid >> 2;
    const int cg = tid & 3;
    const int row = r0 + rl;
    const int xr = tid >> 2, xk = (tid & 3) * 4;

    float acc[16];
#pragma unroll
    for (int i = 0; i < 16; i++) acc[i] = 0.f;

    for (int kb = 0; kb < NFEAT; kb += 16) {
        float4 xv4 = make_float4(0.f, 0.f, 0.f, 0.f);
        if (r0 + xr < N_NODES)
            xv4 = *(const float4*)&x[(size_t)(r0 + xr) * NFEAT + kb + xk];
        __syncthreads();
        *(float4*)&xs[xr][xk] = xv4;
        __syncthreads();
#pragma unroll
        for (int kk = 0; kk < 16; kk++) {
            const float xv = xs[rl][kk];
            const float* wr = &wl[(kb + kk) * D1 + cg * 16];
#pragma unroll
            for (int c = 0; c < 16; c += 4) {
                float4 w4 = *(const float4*)&wr[c];
                acc[c + 0] += xv * w4.x;
                acc[c + 1] += xv * w4.y;
                acc[c + 2] += xv * w4.z;
                acc[c + 3] += xv * w4.w;
            }
        }
    }
    if (row < N_NODES) {
#pragma unroll
        for (int c = 0; c < 16; c += 4) {
            float4 v = make_float4(acc[c], acc[c + 1], acc[c + 2], acc[c + 3]);
            *(float4*)&h1[(size_t)row * D1 + cg * 16 + c] = v;
        }
        // cols cg*16..+15 == heads 2cg, 2cg+1 complete -> full dots in registers
        const int h0 = cg * 2;
        float s0 = 0.f, s1 = 0.f, d0 = 0.f, d1 = 0.f;
#pragma unroll
        for (int j = 0; j < 8; j++) {
            s0 += acc[j] * a_src[h0 * 8 + j];
            d0 += acc[j] * a_dst[h0 * 8 + j];
            s1 += acc[8 + j] * a_src[(h0 + 1) * 8 + j];
            d1 += acc[8 + j] * a_dst[(h0 + 1) * 8 + j];
        }
        als[row * HEADS + h0] = s0;     als[row * HEADS + h0 + 1] = s1;
        ald[row * HEADS + h0] = d0;     ald[row * HEADS + h0 + 1] = d1;
    }
}

// ---------------- K2: bin edges by dst bucket (LDS hist + chunk reservation) ----------------
__global__ __launch_bounds__(256) void bin_kernel(const int* __restrict__ ei,
                                                  int* __restrict__ bcur,
                                                  int2* __restrict__ bin) {
    __shared__ int lcnt[NBUCK];
    __shared__ int lbase[NBUCK];
    const int tid = threadIdx.x;
    for (int b = tid; b < NBUCK; b += 256) lcnt[b] = 0;
    __syncthreads();
    const int e0 = blockIdx.x * BIN_EPB;
    int esrc[BIN_EPT], edst[BIN_EPT], loff[BIN_EPT];
#pragma unroll
    for (int i = 0; i < BIN_EPT; i++) {
        const int e = e0 + i * 256 + tid;
        if (e < E_TOT) {
            edge_src_dst(ei, e, esrc[i], edst[i]);
            loff[i] = atomicAdd(&lcnt[edst[i] >> BSHIFT], 1);
        } else edst[i] = -1;
    }
    __syncthreads();
    for (int b = tid; b < NBUCK; b += 256) {
        const int c = lcnt[b];
        lbase[b] = c ? atomicAdd(&bcur[b], c) : 0;
    }
    __syncthreads();
#pragma unroll
    for (int i = 0; i < BIN_EPT; i++) {
        if (edst[i] >= 0) {
            const int b = edst[i] >> BSHIFT;
            bin[(size_t)b * BCAP + lbase[b] + loff[i]] = make_int2(esrc[i], edst[i]);
        }
    }
}

// ---------------- K3: bucket gather, layer 1 (block=bucket, wave=edge, lane=channel) --------
__global__ __launch_bounds__(512) void bgather1_kernel(const int* __restrict__ bcur,
                                                       const int2* __restrict__ bin,
                                                       const float* __restrict__ h1,
                                                       const float* __restrict__ als,
                                                       const float* __restrict__ ald,
                                                       float* __restrict__ out1) {
    __shared__ float facc[256 * D1];     // 64 KB
    __shared__ float fwsum[256 * HEADS]; // 8 KB
    const int tid = threadIdx.x;
    for (int i = tid; i < 256 * D1; i += 512) facc[i] = 0.f;
    for (int i = tid; i < 256 * HEADS; i += 512) fwsum[i] = 0.f;
    __syncthreads();
    const int bkt = blockIdx.x;
    const int cntb = bcur[bkt];
    const int2* bb = &bin[(size_t)bkt * BCAP];
    const int wave = tid >> 6, c = tid & 63, h = c >> 3;
    int2 ednext = (wave < cntb) ? bb[wave] : make_int2(0, 0);
    for (int i = wave; i < cntb; i += 8) {
        const int2 ed = ednext;
        if (i + 8 < cntb) ednext = bb[i + 8];
        const int src = ed.x, dl = ed.y & 255;
        const float w = __expf(lrelu(als[src * HEADS + h] + ald[ed.y * HEADS + h]));
        atomicAdd(&facc[dl * D1 + c], w * h1[(size_t)src * D1 + c]);
        if ((c & 7) == 0) atomicAdd(&fwsum[dl * HEADS + h], w);
    }
    __syncthreads();
    const int n0 = bkt << BSHIFT;
    for (int i = tid; i < 256 * D1; i += 512) {
        const int n = n0 + (i >> 6);
        if (n < N_NODES)
            out1[(size_t)n * D1 + (i & 63)] =
                facc[i] / (fwsum[(i >> 6) * HEADS + ((i >> 3) & 7)] + 1e-16f);
    }
}

// ---------------- K4: z = elu(out1+b1); h2 = z @ W2; layer-2 logits ----------------
__global__ __launch_bounds__(256) void layer2_node_kernel(const float* __restrict__ out1,
                                                          const float* __restrict__ b1,
                                                          const float* __restrict__ W2,
                                                          const float* __restrict__ a_src2,
                                                          const float* __restrict__ a_dst2,
                                                          float* __restrict__ h2,
                                                          float* __restrict__ als2,
                                                          float* __restrict__ ald2) {
    __shared__ float w2l[D1 * NCLASS];   // 8 KB
    __shared__ float b1l[D1];
    __shared__ float a2l[2 * NCLASS];
    const int tid = threadIdx.x;
    for (int i = tid; i < D1 * NCLASS; i += 256) w2l[i] = W2[i];
    if (tid < D1) b1l[tid] = b1[tid];
    if (tid < NCLASS) a2l[tid] = a_src2[tid];
    else if (tid < 2 * NCLASS) a2l[tid] = a_dst2[tid - NCLASS];
    __syncthreads();

    const int n = blockIdx.x * 256 + tid;
    if (n >= N_NODES) return;
    float acc[NCLASS];
#pragma unroll
    for (int c = 0; c < NCLASS; c++) acc[c] = 0.f;
    float as = 0.f, ad = 0.f;
    const float4* rp = (const float4*)&out1[(size_t)n * D1];
#pragma unroll 2
    for (int k4 = 0; k4 < 16; k4++) {
        const float4 v4 = rp[k4];
        const float vv[4] = {v4.x, v4.y, v4.z, v4.w};
#pragma unroll
        for (int j = 0; j < 4; j++) {
            const int k = k4 * 4 + j;
            float z = vv[j] + b1l[k];
            z = z > 0.f ? z : expm1f(z);   // jax.nn.elu
            const float* wr = &w2l[k * NCLASS];
#pragma unroll
            for (int c = 0; c < NCLASS; c++) acc[c] += z * wr[c];
        }
    }
#pragma unroll
    for (int c = 0; c < NCLASS; c++) { as += acc[c] * a2l[c]; ad += acc[c] * a2l[NCLASS + c]; }
    float4* hp = (float4*)&h2[(size_t)n * NCLASS];
#pragma unroll
    for (int c4 = 0; c4 < NCLASS / 4; c4++)
        hp[c4] = make_float4(acc[c4 * 4], acc[c4 * 4 + 1], acc[c4 * 4 + 2], acc[c4 * 4 + 3]);
    als2[n] = as; ald2[n] = ad;
}

// ---------------- K5: bucket gather, layer 2 (half-wave per edge) ----------------
__global__ __launch_bounds__(512) void bgather2_kernel(const int* __restrict__ bcur,
                                                       const int2* __restrict__ bin,
                                                       const float* __restrict__ h2,
                                                       const float* __restrict__ als2,
                                                       const float* __restrict__ ald2,
                                                       float* __restrict__ out2) {
    __shared__ float sacc[256 * NCLASS]; // 32 KB
    __shared__ float swsum[256];         // 1 KB
    const int tid = threadIdx.x;
    for (int i = tid; i < 256 * NCLASS; i += 512) sacc[i] = 0.f;
    if (tid < 256) swsum[tid] = 0.f;
    __syncthreads();
    const int bkt = blockIdx.x;
    const int cntb = bcur[bkt];
    const int2* bb = &bin[(size_t)bkt * BCAP];
    const int hw = tid >> 5, c = tid & 31;
    int2 ednext = (hw < cntb) ? bb[hw] : make_int2(0, 0);
    for (int i = hw; i < cntb; i += 16) {
        const int2 ed = ednext;
        if (i + 16 < cntb) ednext = bb[i + 16];
        const int src = ed.x, dl = ed.y & 255;
        const float w = __expf(lrelu(als2[src] + ald2[ed.y]));
        atomicAdd(&sacc[dl * NCLASS + c], w * h2[(size_t)src * NCLASS + c]);
        if (c == 0) atomicAdd(&swsum[dl], w);
    }
    __syncthreads();
    const int n0 = bkt << BSHIFT;
    for (int i = tid; i < 256 * NCLASS; i += 512) {
        const int n = n0 + (i >> 5);
        if (n < N_NODES)
            out2[(size_t)n * NCLASS + (i & 31)] = sacc[i] / (swsum[i >> 5] + 1e-16f);
    }
}

// ---------------- K6: + b2, log_softmax ----------------
__global__ __launch_bounds__(256) void logsoftmax_kernel(const float* __restrict__ out2,
                                                         const float* __restrict__ b2,
                                                         float* __restrict__ out) {
    __shared__ float b2l[NCLASS];
    if (threadIdx.x < NCLASS) b2l[threadIdx.x] = b2[threadIdx.x];
    __syncthreads();
    const int n = blockIdx.x * 256 + threadIdx.x;
    if (n >= N_NODES) return;
    float v[NCLASS];
    float mx = -INFINITY;
    const float4* rp = (const float4*)&out2[(size_t)n * NCLASS];
#pragma unroll
    for (int c4 = 0; c4 < NCLASS / 4; c4++) {
        const float4 t = rp[c4];
        v[c4 * 4 + 0] = t.x + b2l[c4 * 4 + 0];
        v[c4 * 4 + 1] = t.y + b2l[c4 * 4 + 1];
        v[c4 * 4 + 2] = t.z + b2l[c4 * 4 + 2];
        v[c4 * 4 + 3] = t.w + b2l[c4 * 4 + 3];
    }
#pragma unroll
    for (int c = 0; c < NCLASS; c++) mx = fmaxf(mx, v[c]);
    float s = 0.f;
#pragma unroll
    for (int c = 0; c < NCLASS; c++) s += __expf(v[c] - mx);
    const float lse = mx + logf(s);
    float4* op = (float4*)&out[(size_t)n * NCLASS];
#pragma unroll
    for (int c4 = 0; c4 < NCLASS / 4; c4++)
        op[c4] = make_float4(v[c4 * 4] - lse, v[c4 * 4 + 1] - lse, v[c4 * 4 + 2] - lse, v[c4 * 4 + 3] - lse);
}

extern "C" void kernel_launch(void* const* d_in, const int* in_sizes, int n_in,
                              void* d_out, int out_size, void* d_ws, size_t ws_size,
                              hipStream_t stream) {
    const float* x      = (const float*)d_in[0];
    const int*   ei     = (const int*)d_in[1];
    const float* W1     = (const float*)d_in[2];
    const float* a_src1 = (const float*)d_in[3];
    const float* a_dst1 = (const float*)d_in[4];
    const float* b1     = (const float*)d_in[5];
    const float* W2     = (const float*)d_in[6];
    const float* a_src2 = (const float*)d_in[7];
    const float* a_dst2 = (const float*)d_in[8];
    const float* b2     = (const float*)d_in[9];
    float* out = (float*)d_out;
    float* ws  = (float*)d_ws;

    float* h1   = ws + OFF_H1;
    float* out1 = ws + OFF_OUT1;
    float* als1 = ws + OFF_ALS1;
    float* ald1 = ws + OFF_ALD1;
    float* als2 = ws + OFF_ALS2;
    float* ald2 = ws + OFF_ALD2;
    int*   bcur = (int*)(ws + OFF_BCUR);
    int2*  bin  = (int2*)(ws + OFF_BIN);
    float* h2   = ws + OFF_H1;             // alias: h1 dead after bgather1
    float* out2 = ws + OFF_H1 + (size_t)N_NODES * NCLASS;

    hipMemsetAsync(bcur, 0, NBUCK * sizeof(int), stream);

    const int NB = (N_NODES + 255) / 256;   // 391

    gemm1_kernel<<<(N_NODES + 63) / 64, 256, 0, stream>>>(x, W1, a_src1, a_dst1, h1, als1, ald1);
    bin_kernel<<<(E_TOT + BIN_EPB - 1) / BIN_EPB, 256, 0, stream>>>(ei, bcur, bin);
    bgather1_kernel<<<NBUCK, 512, 0, stream>>>(bcur, bin, h1, als1, ald1, out1);
    layer2_node_kernel<<<NB, 256, 0, stream>>>(out1, b1, W2, a_src2, a_dst2, h2, als2, ald2);
    bgather2_kernel<<<NBUCK, 512, 0, stream>>>(bcur, bin, h2, als2, ald2, out2);
    logsoftmax_kernel<<<NB, 256, 0, stream>>>(out2, b2, out);
}

// Round 5
// 510.189 us; speedup vs baseline: 2.9582x; 2.9582x over previous
//
#include <hip/hip_runtime.h>
#include <math.h>

#define N_NODES 100000
#define NFEAT 256
#define D1 64          // HEADS*NHID
#define HEADS 8
#define NHID 8
#define NCLASS 32
#define NUM_EDGES 1600000
#define E_TOT 1700000  // + self loops
#define NEG_SLOPE 0.2f

// dst-bucketing: 256 nodes per bucket; CSR stored bucket-strided (no compaction)
#define BSHIFT 8
#define NBUCK 391            // ceil(100000/256)
#define BCAP 5120            // mean edges/bucket 4352, std ~66; +11.6 sigma headroom
#define BIN_EPB 4096         // edges per bin block
#define BIN_EPT 16           // per thread

// ---- workspace layout (float offsets); 67 MB total (< 74.8 MB proven) ----
#define OFF_H1    0            // 6,400,000 ; reused: h2=[0,3.2M), out2=[3.2M,6.4M)
#define OFF_OUT1  6400000      // 6,400,000
#define OFF_ALS1  12800000     // 800,000
#define OFF_ALD1  13600000     // 800,000
#define OFF_ALS2  14400000     // 100,000
#define OFF_ALD2  14500000     // 100,000
#define OFF_BCUR  14600000     // 391 ints (pad to 1024)
#define OFF_ROWP  14601024     // 100,000 (int) CSR row ptr (bucket-strided space)
#define OFF_CNT   14701024     // 100,000 (int) degree
#define OFF_BIN   14801024     // 391*5120 = 2,001,920 ints (packed dl<<20|src)
#define OFF_CSR   16802944     // 391*5120 = 2,001,920 ints (dst-sorted src)

__device__ __forceinline__ float lrelu(float x) { return x >= 0.f ? x : NEG_SLOPE * x; }

__device__ __forceinline__ void edge_src_dst(const int* __restrict__ ei, int e, int& src, int& dst) {
    if (e < NUM_EDGES) { src = ei[e]; dst = ei[NUM_EDGES + e]; }
    else { src = e - NUM_EDGES; dst = e - NUM_EDGES; }
}

// ---------------- K1: h1 = x @ W1, fused per-(node,head) attention logit dots ----------------
__global__ __launch_bounds__(256) void gemm1_kernel(const float* __restrict__ x,
                                                    const float* __restrict__ W1,
                                                    const float* __restrict__ a_src,
                                                    const float* __restrict__ a_dst,
                                                    float* __restrict__ h1,
                                                    float* __restrict__ als,
                                                    float* __restrict__ ald) {
    __shared__ float wl[NFEAT * D1];   // 64 KB: whole W1
    __shared__ float xs[64][20];
    const int tid = threadIdx.x;
    for (int i = tid * 4; i < NFEAT * D1; i += 256 * 4)
        *(float4*)&wl[i] = *(const float4*)&W1[i];

    const int r0 = blockIdx.x * 64;
    const int rl = tid >> 2;
    const int cg = tid & 3;
    const int row = r0 + rl;
    const int xr = tid >> 2, xk = (tid & 3) * 4;

    float acc[16];
#pragma unroll
    for (int i = 0; i < 16; i++) acc[i] = 0.f;

    for (int kb = 0; kb < NFEAT; kb += 16) {
        float4 xv4 = make_float4(0.f, 0.f, 0.f, 0.f);
        if (r0 + xr < N_NODES)
            xv4 = *(const float4*)&x[(size_t)(r0 + xr) * NFEAT + kb + xk];
        __syncthreads();
        *(float4*)&xs[xr][xk] = xv4;
        __syncthreads();
#pragma unroll
        for (int kk = 0; kk < 16; kk++) {
            const float xv = xs[rl][kk];
            const float* wr = &wl[(kb + kk) * D1 + cg * 16];
#pragma unroll
            for (int c = 0; c < 16; c += 4) {
                float4 w4 = *(const float4*)&wr[c];
                acc[c + 0] += xv * w4.x;
                acc[c + 1] += xv * w4.y;
                acc[c + 2] += xv * w4.z;
                acc[c + 3] += xv * w4.w;
            }
        }
    }
    if (row < N_NODES) {
#pragma unroll
        for (int c = 0; c < 16; c += 4) {
            float4 v = make_float4(acc[c], acc[c + 1], acc[c + 2], acc[c + 3]);
            *(float4*)&h1[(size_t)row * D1 + cg * 16 + c] = v;
        }
        // cols cg*16..+15 == heads 2cg, 2cg+1 complete -> full dots in registers
        const int h0 = cg * 2;
        float s0 = 0.f, s1 = 0.f, d0 = 0.f, d1 = 0.f;
#pragma unroll
        for (int j = 0; j < 8; j++) {
            s0 += acc[j] * a_src[h0 * 8 + j];
            d0 += acc[j] * a_dst[h0 * 8 + j];
            s1 += acc[8 + j] * a_src[(h0 + 1) * 8 + j];
            d1 += acc[8 + j] * a_dst[(h0 + 1) * 8 + j];
        }
        als[row * HEADS + h0] = s0;     als[row * HEADS + h0 + 1] = s1;
        ald[row * HEADS + h0] = d0;     ald[row * HEADS + h0 + 1] = d1;
    }
}

// ---------------- K2: bin edges by dst bucket (LDS hist + chunk reservation) ----------------
// packed entry: (dst&255)<<20 | src   (src < 2^17)
__global__ __launch_bounds__(256) void bin_kernel(const int* __restrict__ ei,
                                                  int* __restrict__ bcur,
                                                  int* __restrict__ bin) {
    __shared__ int lcnt[NBUCK];
    __shared__ int lbase[NBUCK];
    const int tid = threadIdx.x;
    for (int b = tid; b < NBUCK; b += 256) lcnt[b] = 0;
    __syncthreads();
    const int e0 = blockIdx.x * BIN_EPB;
    int pk[BIN_EPT], bk[BIN_EPT], loff[BIN_EPT];
#pragma unroll
    for (int i = 0; i < BIN_EPT; i++) {
        const int e = e0 + i * 256 + tid;
        if (e < E_TOT) {
            int src, dst; edge_src_dst(ei, e, src, dst);
            bk[i] = dst >> BSHIFT;
            pk[i] = ((dst & 255) << 20) | src;
            loff[i] = atomicAdd(&lcnt[bk[i]], 1);
        } else bk[i] = -1;
    }
    __syncthreads();
    for (int b = tid; b < NBUCK; b += 256) {
        const int c = lcnt[b];
        lbase[b] = c ? atomicAdd(&bcur[b], c) : 0;
    }
    __syncthreads();
#pragma unroll
    for (int i = 0; i < BIN_EPT; i++) {
        if (bk[i] >= 0)
            bin[(size_t)bk[i] * BCAP + lbase[bk[i]] + loff[i]] = pk[i];
    }
}

// ---------------- K3: per-bucket LDS counting sort -> dst-sorted CSR (coalesced writes) ------
__global__ __launch_bounds__(256) void bsort_kernel(const int* __restrict__ bcur,
                                                    const int* __restrict__ bin,
                                                    int* __restrict__ csr,
                                                    int* __restrict__ row_ptr,
                                                    int* __restrict__ cnt) {
    __shared__ int hcnt[256];
    __shared__ int hpre[256];
    __shared__ int cur[256];
    __shared__ int ssrc[BCAP];   // 20 KB
    const int tid = threadIdx.x;
    const int bkt = blockIdx.x;
    const int cntb = bcur[bkt];
    const int base = bkt * BCAP;
    hcnt[tid] = 0;
    __syncthreads();
    for (int i = tid; i < cntb; i += 256)
        atomicAdd(&hcnt[bin[base + i] >> 20], 1);
    __syncthreads();
    const int myc = hcnt[tid];
    hpre[tid] = myc;
    __syncthreads();
    for (int off = 1; off < 256; off <<= 1) {
        const int t = (tid >= off) ? hpre[tid - off] : 0;
        __syncthreads();
        hpre[tid] += t;
        __syncthreads();
    }
    const int exc = hpre[tid] - myc;   // exclusive prefix
    cur[tid] = exc;
    __syncthreads();
    for (int i = tid; i < cntb; i += 256) {
        const int v = bin[base + i];
        const int pos = atomicAdd(&cur[v >> 20], 1);
        ssrc[pos] = v & 0xFFFFF;
    }
    __syncthreads();
    for (int i = tid; i < cntb; i += 256) csr[base + i] = ssrc[i];
    const int n = (bkt << BSHIFT) + tid;
    if (n < N_NODES) { row_ptr[n] = base + exc; cnt[n] = myc; }
}

// ---------------- K4: gather aggregation, layer 1 (1 wave/node, lane=channel, fused softmax) --
__global__ __launch_bounds__(256) void gather1_kernel(const int* __restrict__ row_ptr,
                                                      const int* __restrict__ cnt,
                                                      const int* __restrict__ csr_src,
                                                      const float* __restrict__ h1,
                                                      const float* __restrict__ als,
                                                      const float* __restrict__ ald,
                                                      float* __restrict__ out1) {
    const int tid = threadIdx.x;
    const int n = blockIdx.x * 4 + (tid >> 6);   // grid == N_NODES waves exactly
    const int c = tid & 63, h = c >> 3;
    const int start = row_ptr[n];
    const int deg = cnt[n];
    const float aldn = ald[n * HEADS + h];
    float acc = 0.f, wsum = 0.f;
    int snext = csr_src[start];
    for (int i = 0; i < deg; i++) {
        const int s = snext;
        if (i + 1 < deg) snext = csr_src[start + i + 1];
        const float w = __expf(lrelu(als[s * HEADS + h] + aldn));
        acc = fmaf(h1[(size_t)s * D1 + c], w, acc);
        wsum += w;
    }
    out1[(size_t)n * D1 + c] = acc / (wsum + 1e-16f);
}

// ---------------- K5: z = elu(out1+b1); h2 = z @ W2; layer-2 logits ----------------
__global__ __launch_bounds__(256) void layer2_node_kernel(const float* __restrict__ out1,
                                                          const float* __restrict__ b1,
                                                          const float* __restrict__ W2,
                                                          const float* __restrict__ a_src2,
                                                          const float* __restrict__ a_dst2,
                                                          float* __restrict__ h2,
                                                          float* __restrict__ als2,
                                                          float* __restrict__ ald2) {
    __shared__ float w2l[D1 * NCLASS];   // 8 KB
    __shared__ float b1l[D1];
    __shared__ float a2l[2 * NCLASS];
    const int tid = threadIdx.x;
    for (int i = tid; i < D1 * NCLASS; i += 256) w2l[i] = W2[i];
    if (tid < D1) b1l[tid] = b1[tid];
    if (tid < NCLASS) a2l[tid] = a_src2[tid];
    else if (tid < 2 * NCLASS) a2l[tid] = a_dst2[tid - NCLASS];
    __syncthreads();

    const int n = blockIdx.x * 256 + tid;
    if (n >= N_NODES) return;
    float acc[NCLASS];
#pragma unroll
    for (int c = 0; c < NCLASS; c++) acc[c] = 0.f;
    float as = 0.f, ad = 0.f;
    const float4* rp = (const float4*)&out1[(size_t)n * D1];
#pragma unroll 2
    for (int k4 = 0; k4 < 16; k4++) {
        const float4 v4 = rp[k4];
        const float vv[4] = {v4.x, v4.y, v4.z, v4.w};
#pragma unroll
        for (int j = 0; j < 4; j++) {
            const int k = k4 * 4 + j;
            float z = vv[j] + b1l[k];
            z = z > 0.f ? z : expm1f(z);   // jax.nn.elu
            const float* wr = &w2l[k * NCLASS];
#pragma unroll
            for (int c = 0; c < NCLASS; c++) acc[c] += z * wr[c];
        }
    }
#pragma unroll
    for (int c = 0; c < NCLASS; c++) { as += acc[c] * a2l[c]; ad += acc[c] * a2l[NCLASS + c]; }
    float4* hp = (float4*)&h2[(size_t)n * NCLASS];
#pragma unroll
    for (int c4 = 0; c4 < NCLASS / 4; c4++)
        hp[c4] = make_float4(acc[c4 * 4], acc[c4 * 4 + 1], acc[c4 * 4 + 2], acc[c4 * 4 + 3]);
    als2[n] = as; ald2[n] = ad;
}

// ---------------- K6: gather aggregation, layer 2 (half-wave/node, fused softmax) ----------
__global__ __launch_bounds__(256) void gather2_kernel(const int* __restrict__ row_ptr,
                                                      const int* __restrict__ cnt,
                                                      const int* __restrict__ csr_src,
                                                      const float* __restrict__ h2,
                                                      const float* __restrict__ als2,
                                                      const float* __restrict__ ald2,
                                                      float* __restrict__ out2) {
    const int tid = threadIdx.x;
    const int n = blockIdx.x * 8 + (tid >> 5);   // grid == N_NODES half-waves exactly
    const int c = tid & 31;
    const int start = row_ptr[n];
    const int deg = cnt[n];
    const float aldn = ald2[n];
    float acc = 0.f, wsum = 0.f;
    int snext = csr_src[start];
    for (int i = 0; i < deg; i++) {
        const int s = snext;
        if (i + 1 < deg) snext = csr_src[start + i + 1];
        const float w = __expf(lrelu(als2[s] + aldn));
        acc = fmaf(h2[(size_t)s * NCLASS + c], w, acc);
        wsum += w;
    }
    out2[(size_t)n * NCLASS + c] = acc / (wsum + 1e-16f);
}

// ---------------- K7: + b2, log_softmax ----------------
__global__ __launch_bounds__(256) void logsoftmax_kernel(const float* __restrict__ out2,
                                                         const float* __restrict__ b2,
                                                         float* __restrict__ out) {
    __shared__ float b2l[NCLASS];
    if (threadIdx.x < NCLASS) b2l[threadIdx.x] = b2[threadIdx.x];
    __syncthreads();
    const int n = blockIdx.x * 256 + threadIdx.x;
    if (n >= N_NODES) return;
    float v[NCLASS];
    float mx = -INFINITY;
    const float4* rp = (const float4*)&out2[(size_t)n * NCLASS];
#pragma unroll
    for (int c4 = 0; c4 < NCLASS / 4; c4++) {
        const float4 t = rp[c4];
        v[c4 * 4 + 0] = t.x + b2l[c4 * 4 + 0];
        v[c4 * 4 + 1] = t.y + b2l[c4 * 4 + 1];
        v[c4 * 4 + 2] = t.z + b2l[c4 * 4 + 2];
        v[c4 * 4 + 3] = t.w + b2l[c4 * 4 + 3];
    }
#pragma unroll
    for (int c = 0; c < NCLASS; c++) mx = fmaxf(mx, v[c]);
    float s = 0.f;
#pragma unroll
    for (int c = 0; c < NCLASS; c++) s += __expf(v[c] - mx);
    const float lse = mx + logf(s);
    float4* op = (float4*)&out[(size_t)n * NCLASS];
#pragma unroll
    for (int c4 = 0; c4 < NCLASS / 4; c4++)
        op[c4] = make_float4(v[c4 * 4] - lse, v[c4 * 4 + 1] - lse, v[c4 * 4 + 2] - lse, v[c4 * 4 + 3] - lse);
}

extern "C" void kernel_launch(void* const* d_in, const int* in_sizes, int n_in,
                              void* d_out, int out_size, void* d_ws, size_t ws_size,
                              hipStream_t stream) {
    const float* x      = (const float*)d_in[0];
    const int*   ei     = (const int*)d_in[1];
    const float* W1     = (const float*)d_in[2];
    const float* a_src1 = (const float*)d_in[3];
    const float* a_dst1 = (const float*)d_in[4];
    const float* b1     = (const float*)d_in[5];
    const float* W2     = (const float*)d_in[6];
    const float* a_src2 = (const float*)d_in[7];
    const float* a_dst2 = (const float*)d_in[8];
    const float* b2     = (const float*)d_in[9];
    float* out = (float*)d_out;
    float* ws  = (float*)d_ws;

    float* h1      = ws + OFF_H1;
    float* out1    = ws + OFF_OUT1;
    float* als1    = ws + OFF_ALS1;
    float* ald1    = ws + OFF_ALD1;
    float* als2    = ws + OFF_ALS2;
    float* ald2    = ws + OFF_ALD2;
    int*   bcur    = (int*)(ws + OFF_BCUR);
    int*   row_ptr = (int*)(ws + OFF_ROWP);
    int*   cnt     = (int*)(ws + OFF_CNT);
    int*   bin     = (int*)(ws + OFF_BIN);
    int*   csr     = (int*)(ws + OFF_CSR);
    float* h2      = ws + OFF_H1;             // alias: h1 dead after gather1
    float* out2    = ws + OFF_H1 + (size_t)N_NODES * NCLASS;

    hipMemsetAsync(bcur, 0, NBUCK * sizeof(int), stream);

    const int NB = (N_NODES + 255) / 256;   // 391

    gemm1_kernel<<<(N_NODES + 63) / 64, 256, 0, stream>>>(x, W1, a_src1, a_dst1, h1, als1, ald1);
    bin_kernel<<<(E_TOT + BIN_EPB - 1) / BIN_EPB, 256, 0, stream>>>(ei, bcur, bin);
    bsort_kernel<<<NBUCK, 256, 0, stream>>>(bcur, bin, csr, row_ptr, cnt);
    gather1_kernel<<<N_NODES / 4, 256, 0, stream>>>(row_ptr, cnt, csr, h1, als1, ald1, out1);
    layer2_node_kernel<<<NB, 256, 0, stream>>>(out1, b1, W2, a_src2, a_dst2, h2, als2, ald2);
    gather2_kernel<<<N_NODES / 8, 256, 0, stream>>>(row_ptr, cnt, csr, h2, als2, ald2, out2);
    logsoftmax_kernel<<<NB, 256, 0, stream>>>(out2, b2, out);
}

// Round 7
// 431.081 us; speedup vs baseline: 3.5010x; 1.1835x over previous
//
#include <hip/hip_runtime.h>
#include <math.h>

#define N_NODES 100000
#define NFEAT 256
#define D1 64          // HEADS*NHID
#define HEADS 8
#define NHID 8
#define NCLASS 32
#define NUM_EDGES 1600000
#define E_TOT 1700000  // + self loops
#define NEG_SLOPE 0.2f

// dst-bucketing: 256 nodes per bucket; CSR stored bucket-strided (no compaction)
#define BSHIFT 8
#define NBUCK 391            // ceil(100000/256)
#define BCAP 5120            // mean edges/bucket 4352, std ~66; +11.6 sigma headroom
#define BIN_EPB 4096
#define BIN_EPT 16

// gemm1 tiling
#define G1_ROWS 128
#define XS_STRIDE 20         // float4-aligned pad; xs reads 4-way aliased (1.58x) - acceptable
// LESSON (r6): do NOT xor-swizzle xs storage here -- read addresses are positions
// (swizzle-invariant), and the permuted k-order turned wl's free 2-way aliasing
// into 8-way. The r6 version also mispaired x element k with W element k^ksw.

// ---- workspace layout (float offsets); 67 MB total ----
#define OFF_H1    0            // 6,400,000 ; reused: h2=[0,3.2M), out2=[3.2M,6.4M)
#define OFF_OUT1  6400000
#define OFF_ALS1  12800000
#define OFF_ALD1  13600000
#define OFF_ALS2  14400000
#define OFF_ALD2  14500000
#define OFF_BCUR  14600000     // 391 ints (pad to 1024)
#define OFF_ROWP  14601024
#define OFF_CNT   14701024
#define OFF_BIN   14801024     // 391*5120 ints (packed dl<<20|src)
#define OFF_CSR   16802944     // 391*5120 ints (dst-sorted src)

// LESSON (r4): wave-per-node x 25k waves >> block-per-bucket x 391 blocks on this
// graph (mean deg 17) -- TLP is the latency hider; LDS-acc buckets starve the GPU.

__device__ __forceinline__ float lrelu(float x) { return x >= 0.f ? x : NEG_SLOPE * x; }

__device__ __forceinline__ void edge_src_dst(const int* __restrict__ ei, int e, int& src, int& dst) {
    if (e < NUM_EDGES) { src = ei[e]; dst = ei[NUM_EDGES + e]; }
    else { src = e - NUM_EDGES; dst = e - NUM_EDGES; }
}

// ---------------- K1: h1 = x @ W1, 4x8 register tile, fused logit dots ----------------
__global__ __launch_bounds__(256) void gemm1_kernel(const float* __restrict__ x,
                                                    const float* __restrict__ W1,
                                                    const float* __restrict__ a_src,
                                                    const float* __restrict__ a_dst,
                                                    float* __restrict__ h1,
                                                    float* __restrict__ als,
                                                    float* __restrict__ ald) {
    __shared__ float wl[NFEAT * D1];            // 64 KB: whole W1
    __shared__ float xs[G1_ROWS * XS_STRIDE];   // 10 KB
    const int tid = threadIdx.x;
    for (int i = tid * 4; i < NFEAT * D1; i += 256 * 4)
        *(float4*)&wl[i] = *(const float4*)&W1[i];

    const int rg = tid >> 3;        // 0..31, owns rows rg*4..rg*4+3
    const int cg = tid & 7;         // head cg, cols cg*8..cg*8+7
    const int rg4 = rg * 4;
    const int r0 = blockIdx.x * G1_ROWS;
    // staging map: thread handles float4 f=tid and f=tid+256; row=f>>2, k4=(f&3)*4
    const int rr0 = tid >> 2,         kk0 = (tid & 3) * 4;
    const int rr1 = (tid + 256) >> 2, kk1 = kk0;

    float acc[4][8];
#pragma unroll
    for (int j = 0; j < 4; j++)
#pragma unroll
        for (int c = 0; c < 8; c++) acc[j][c] = 0.f;

    for (int kb = 0; kb < NFEAT; kb += 16) {
        float4 xv0 = make_float4(0.f, 0.f, 0.f, 0.f), xv1 = xv0;
        if (r0 + rr0 < N_NODES) xv0 = *(const float4*)&x[(size_t)(r0 + rr0) * NFEAT + kb + kk0];
        if (r0 + rr1 < N_NODES) xv1 = *(const float4*)&x[(size_t)(r0 + rr1) * NFEAT + kb + kk1];
        __syncthreads();
        *(float4*)&xs[rr0 * XS_STRIDE + kk0] = xv0;
        *(float4*)&xs[rr1 * XS_STRIDE + kk1] = xv1;
        __syncthreads();
#pragma unroll
        for (int k = 0; k < 16; k++) {
            const float xa[4] = {xs[(rg4 + 0) * XS_STRIDE + k], xs[(rg4 + 1) * XS_STRIDE + k],
                                 xs[(rg4 + 2) * XS_STRIDE + k], xs[(rg4 + 3) * XS_STRIDE + k]};
            const float4 wa = *(const float4*)&wl[(kb + k) * D1 + cg * 8];
            const float4 wb = *(const float4*)&wl[(kb + k) * D1 + cg * 8 + 4];
            const float wv[8] = {wa.x, wa.y, wa.z, wa.w, wb.x, wb.y, wb.z, wb.w};
#pragma unroll
            for (int j = 0; j < 4; j++)
#pragma unroll
                for (int c = 0; c < 8; c++) acc[j][c] = fmaf(xa[j], wv[c], acc[j][c]);
        }
    }
    // epilogue: thread owns head cg completely for its 4 rows
    float asv[8], adv[8];
#pragma unroll
    for (int c = 0; c < 8; c++) { asv[c] = a_src[cg * 8 + c]; adv[c] = a_dst[cg * 8 + c]; }
#pragma unroll
    for (int j = 0; j < 4; j++) {
        const int row = r0 + rg4 + j;
        if (row < N_NODES) {
            *(float4*)&h1[(size_t)row * D1 + cg * 8] =
                make_float4(acc[j][0], acc[j][1], acc[j][2], acc[j][3]);
            *(float4*)&h1[(size_t)row * D1 + cg * 8 + 4] =
                make_float4(acc[j][4], acc[j][5], acc[j][6], acc[j][7]);
            float s = 0.f, d = 0.f;
#pragma unroll
            for (int c = 0; c < 8; c++) { s += acc[j][c] * asv[c]; d += acc[j][c] * adv[c]; }
            als[row * HEADS + cg] = s;
            ald[row * HEADS + cg] = d;
        }
    }
}

// ---------------- K2: bin edges by dst bucket (LDS hist + chunk reservation) ----------------
// packed entry: (dst&255)<<20 | src   (src < 2^17)
__global__ __launch_bounds__(256) void bin_kernel(const int* __restrict__ ei,
                                                  int* __restrict__ bcur,
                                                  int* __restrict__ bin) {
    __shared__ int lcnt[NBUCK];
    __shared__ int lbase[NBUCK];
    const int tid = threadIdx.x;
    for (int b = tid; b < NBUCK; b += 256) lcnt[b] = 0;
    __syncthreads();
    const int e0 = blockIdx.x * BIN_EPB;
    int pk[BIN_EPT], bk[BIN_EPT], loff[BIN_EPT];
#pragma unroll
    for (int i = 0; i < BIN_EPT; i++) {
        const int e = e0 + i * 256 + tid;
        if (e < E_TOT) {
            int src, dst; edge_src_dst(ei, e, src, dst);
            bk[i] = dst >> BSHIFT;
            pk[i] = ((dst & 255) << 20) | src;
            loff[i] = atomicAdd(&lcnt[bk[i]], 1);
        } else bk[i] = -1;
    }
    __syncthreads();
    for (int b = tid; b < NBUCK; b += 256) {
        const int c = lcnt[b];
        lbase[b] = c ? atomicAdd(&bcur[b], c) : 0;
    }
    __syncthreads();
#pragma unroll
    for (int i = 0; i < BIN_EPT; i++) {
        if (bk[i] >= 0)
            bin[(size_t)bk[i] * BCAP + lbase[bk[i]] + loff[i]] = pk[i];
    }
}

// ---------------- K3: per-bucket LDS counting sort -> dst-sorted CSR ----------------
__global__ __launch_bounds__(256) void bsort_kernel(const int* __restrict__ bcur,
                                                    const int* __restrict__ bin,
                                                    int* __restrict__ csr,
                                                    int* __restrict__ row_ptr,
                                                    int* __restrict__ cnt) {
    __shared__ int hcnt[256];
    __shared__ int hpre[256];
    __shared__ int cur[256];
    __shared__ int ssrc[BCAP];   // 20 KB
    const int tid = threadIdx.x;
    const int bkt = blockIdx.x;
    const int cntb = bcur[bkt];
    const int base = bkt * BCAP;
    hcnt[tid] = 0;
    __syncthreads();
    for (int i = tid; i < cntb; i += 256)
        atomicAdd(&hcnt[bin[base + i] >> 20], 1);
    __syncthreads();
    const int myc = hcnt[tid];
    hpre[tid] = myc;
    __syncthreads();
    for (int off = 1; off < 256; off <<= 1) {
        const int t = (tid >= off) ? hpre[tid - off] : 0;
        __syncthreads();
        hpre[tid] += t;
        __syncthreads();
    }
    const int exc = hpre[tid] - myc;
    cur[tid] = exc;
    __syncthreads();
    for (int i = tid; i < cntb; i += 256) {
        const int v = bin[base + i];
        const int pos = atomicAdd(&cur[v >> 20], 1);
        ssrc[pos] = v & 0xFFFFF;
    }
    __syncthreads();
    for (int i = tid; i < cntb; i += 256) csr[base + i] = ssrc[i];
    const int n = (bkt << BSHIFT) + tid;
    if (n < N_NODES) { row_ptr[n] = base + exc; cnt[n] = myc; }
}

// ---------------- K4: gather layer 1 -- wave/node, 32 lanes x float2, 2 edge-slots ----------
__global__ __launch_bounds__(256) void gather1_kernel(const int* __restrict__ row_ptr,
                                                      const int* __restrict__ cnt,
                                                      const int* __restrict__ csr_src,
                                                      const float* __restrict__ h1,
                                                      const float* __restrict__ als,
                                                      const float* __restrict__ ald,
                                                      float* __restrict__ out1) {
    const int tid = threadIdx.x;
    const int n = blockIdx.x * 4 + (tid >> 6);   // grid == N_NODES/4 exactly
    const int l = tid & 63;
    const int half = l >> 5;                     // edge slot 0/1
    const int c2 = l & 31;                       // channels 2c2, 2c2+1
    const int h = c2 >> 2;                       // head (both channels in same head)
    const int start = row_ptr[n];
    const int deg = cnt[n];
    const float aldn = ald[n * HEADS + h];
    float ax = 0.f, ay = 0.f, wsum = 0.f;
    int snext = (half < deg) ? csr_src[start + half] : 0;
    for (int i = half; i < deg; i += 2) {
        const int s = snext;
        if (i + 2 < deg) snext = csr_src[start + i + 2];
        const float w = __expf(lrelu(als[s * HEADS + h] + aldn));
        const float2 hv = *(const float2*)&h1[(size_t)s * D1 + 2 * c2];
        ax = fmaf(hv.x, w, ax);
        ay = fmaf(hv.y, w, ay);
        wsum += w;
    }
    ax += __shfl_down(ax, 32, 64);
    ay += __shfl_down(ay, 32, 64);
    wsum += __shfl_down(wsum, 32, 64);
    if (half == 0) {
        const float inv = 1.f / (wsum + 1e-16f);
        *(float2*)&out1[(size_t)n * D1 + 2 * c2] = make_float2(ax * inv, ay * inv);
    }
}

// ---------------- K5: z = elu(out1+b1); h2 = z @ W2; layer-2 logits ----------------
__global__ __launch_bounds__(256) void layer2_node_kernel(const float* __restrict__ out1,
                                                          const float* __restrict__ b1,
                                                          const float* __restrict__ W2,
                                                          const float* __restrict__ a_src2,
                                                          const float* __restrict__ a_dst2,
                                                          float* __restrict__ h2,
                                                          float* __restrict__ als2,
                                                          float* __restrict__ ald2) {
    __shared__ float w2l[D1 * NCLASS];   // 8 KB
    __shared__ float b1l[D1];
    __shared__ float a2l[2 * NCLASS];
    const int tid = threadIdx.x;
    for (int i = tid; i < D1 * NCLASS; i += 256) w2l[i] = W2[i];
    if (tid < D1) b1l[tid] = b1[tid];
    if (tid < NCLASS) a2l[tid] = a_src2[tid];
    else if (tid < 2 * NCLASS) a2l[tid] = a_dst2[tid - NCLASS];
    __syncthreads();

    const int n = blockIdx.x * 256 + tid;
    if (n >= N_NODES) return;
    float acc[NCLASS];
#pragma unroll
    for (int c = 0; c < NCLASS; c++) acc[c] = 0.f;
    float as = 0.f, ad = 0.f;
    const float4* rp = (const float4*)&out1[(size_t)n * D1];
#pragma unroll 2
    for (int k4 = 0; k4 < 16; k4++) {
        const float4 v4 = rp[k4];
        const float vv[4] = {v4.x, v4.y, v4.z, v4.w};
#pragma unroll
        for (int j = 0; j < 4; j++) {
            const int k = k4 * 4 + j;
            float z = vv[j] + b1l[k];
            z = z > 0.f ? z : expm1f(z);   // jax.nn.elu
            const float* wr = &w2l[k * NCLASS];
#pragma unroll
            for (int c = 0; c < NCLASS; c++) acc[c] += z * wr[c];
        }
    }
#pragma unroll
    for (int c = 0; c < NCLASS; c++) { as += acc[c] * a2l[c]; ad += acc[c] * a2l[NCLASS + c]; }
    float4* hp = (float4*)&h2[(size_t)n * NCLASS];
#pragma unroll
    for (int c4 = 0; c4 < NCLASS / 4; c4++)
        hp[c4] = make_float4(acc[c4 * 4], acc[c4 * 4 + 1], acc[c4 * 4 + 2], acc[c4 * 4 + 3]);
    als2[n] = as; ald2[n] = ad;
}

// ---------------- K6: gather layer 2 -- wave/node, 16 lanes x float2, 4 edge-slots ----------
__global__ __launch_bounds__(256) void gather2_kernel(const int* __restrict__ row_ptr,
                                                      const int* __restrict__ cnt,
                                                      const int* __restrict__ csr_src,
                                                      const float* __restrict__ h2,
                                                      const float* __restrict__ als2,
                                                      const float* __restrict__ ald2,
                                                      float* __restrict__ out2) {
    const int tid = threadIdx.x;
    const int n = blockIdx.x * 4 + (tid >> 6);   // grid == N_NODES/4 exactly
    const int l = tid & 63;
    const int q = l >> 4;                        // edge slot 0..3
    const int c2 = l & 15;                       // channels 2c2, 2c2+1
    const int start = row_ptr[n];
    const int deg = cnt[n];
    const float aldn = ald2[n];
    float ax = 0.f, ay = 0.f, wsum = 0.f;
    int snext = (q < deg) ? csr_src[start + q] : 0;
    for (int i = q; i < deg; i += 4) {
        const int s = snext;
        if (i + 4 < deg) snext = csr_src[start + i + 4];
        const float w = __expf(lrelu(als2[s] + aldn));
        const float2 hv = *(const float2*)&h2[(size_t)s * NCLASS + 2 * c2];
        ax = fmaf(hv.x, w, ax);
        ay = fmaf(hv.y, w, ay);
        wsum += w;
    }
    ax += __shfl_down(ax, 32, 64);
    ay += __shfl_down(ay, 32, 64);
    wsum += __shfl_down(wsum, 32, 64);
    ax += __shfl_down(ax, 16, 64);
    ay += __shfl_down(ay, 16, 64);
    wsum += __shfl_down(wsum, 16, 64);
    if (q == 0) {
        const float inv = 1.f / (wsum + 1e-16f);
        *(float2*)&out2[(size_t)n * NCLASS + 2 * c2] = make_float2(ax * inv, ay * inv);
    }
}

// ---------------- K7: + b2, log_softmax ----------------
__global__ __launch_bounds__(256) void logsoftmax_kernel(const float* __restrict__ out2,
                                                         const float* __restrict__ b2,
                                                         float* __restrict__ out) {
    __shared__ float b2l[NCLASS];
    if (threadIdx.x < NCLASS) b2l[threadIdx.x] = b2[threadIdx.x];
    __syncthreads();
    const int n = blockIdx.x * 256 + threadIdx.x;
    if (n >= N_NODES) return;
    float v[NCLASS];
    float mx = -INFINITY;
    const float4* rp = (const float4*)&out2[(size_t)n * NCLASS];
#pragma unroll
    for (int c4 = 0; c4 < NCLASS / 4; c4++) {
        const float4 t = rp[c4];
        v[c4 * 4 + 0] = t.x + b2l[c4 * 4 + 0];
        v[c4 * 4 + 1] = t.y + b2l[c4 * 4 + 1];
        v[c4 * 4 + 2] = t.z + b2l[c4 * 4 + 2];
        v[c4 * 4 + 3] = t.w + b2l[c4 * 4 + 3];
    }
#pragma unroll
    for (int c = 0; c < NCLASS; c++) mx = fmaxf(mx, v[c]);
    float s = 0.f;
#pragma unroll
    for (int c = 0; c < NCLASS; c++) s += __expf(v[c] - mx);
    const float lse = mx + logf(s);
    float4* op = (float4*)&out[(size_t)n * NCLASS];
#pragma unroll
    for (int c4 = 0; c4 < NCLASS / 4; c4++)
        op[c4] = make_float4(v[c4 * 4] - lse, v[c4 * 4 + 1] - lse, v[c4 * 4 + 2] - lse, v[c4 * 4 + 3] - lse);
}

extern "C" void kernel_launch(void* const* d_in, const int* in_sizes, int n_in,
                              void* d_out, int out_size, void* d_ws, size_t ws_size,
                              hipStream_t stream) {
    const float* x      = (const float*)d_in[0];
    const int*   ei     = (const int*)d_in[1];
    const float* W1     = (const float*)d_in[2];
    const float* a_src1 = (const float*)d_in[3];
    const float* a_dst1 = (const float*)d_in[4];
    const float* b1     = (const float*)d_in[5];
    const float* W2     = (const float*)d_in[6];
    const float* a_src2 = (const float*)d_in[7];
    const float* a_dst2 = (const float*)d_in[8];
    const float* b2     = (const float*)d_in[9];
    float* out = (float*)d_out;
    float* ws  = (float*)d_ws;

    float* h1      = ws + OFF_H1;
    float* out1    = ws + OFF_OUT1;
    float* als1    = ws + OFF_ALS1;
    float* ald1    = ws + OFF_ALD1;
    float* als2    = ws + OFF_ALS2;
    float* ald2    = ws + OFF_ALD2;
    int*   bcur    = (int*)(ws + OFF_BCUR);
    int*   row_ptr = (int*)(ws + OFF_ROWP);
    int*   cnt     = (int*)(ws + OFF_CNT);
    int*   bin     = (int*)(ws + OFF_BIN);
    int*   csr     = (int*)(ws + OFF_CSR);
    float* h2      = ws + OFF_H1;             // alias: h1 dead after gather1
    float* out2    = ws + OFF_H1 + (size_t)N_NODES * NCLASS;

    hipMemsetAsync(bcur, 0, NBUCK * sizeof(int), stream);

    const int NB = (N_NODES + 255) / 256;   // 391

    gemm1_kernel<<<(N_NODES + G1_ROWS - 1) / G1_ROWS, 256, 0, stream>>>(x, W1, a_src1, a_dst1,
                                                                        h1, als1, ald1);
    bin_kernel<<<(E_TOT + BIN_EPB - 1) / BIN_EPB, 256, 0, stream>>>(ei, bcur, bin);
    bsort_kernel<<<NBUCK, 256, 0, stream>>>(bcur, bin, csr, row_ptr, cnt);
    gather1_kernel<<<N_NODES / 4, 256, 0, stream>>>(row_ptr, cnt, csr, h1, als1, ald1, out1);
    layer2_node_kernel<<<NB, 256, 0, stream>>>(out1, b1, W2, a_src2, a_dst2, h2, als2, ald2);
    gather2_kernel<<<N_NODES / 4, 256, 0, stream>>>(row_ptr, cnt, csr, h2, als2, ald2, out2);
    logsoftmax_kernel<<<NB, 256, 0, stream>>>(out2, b2, out);
}

// Round 8
// 418.877 us; speedup vs baseline: 3.6031x; 1.0291x over previous
//
#include <hip/hip_runtime.h>
#include <math.h>

#define N_NODES 100000
#define NFEAT 256
#define D1 64          // HEADS*NHID
#define HEADS 8
#define NHID 8
#define NCLASS 32
#define NUM_EDGES 1600000
#define E_TOT 1700000  // + self loops
#define NEG_SLOPE 0.2f

// dst-bucketing: 256 nodes per bucket; CSR stored bucket-strided (no compaction)
#define BSHIFT 8
#define NBUCK 391            // ceil(100000/256)
#define BCAP 5120            // mean edges/bucket 4352, std ~66; +11.6 sigma headroom
#define BIN_EPB 4096
#define BIN_EPT 16

// gemm1 tiling: per-kb W tile (4KB) + xs stride 17 -> ~13KB LDS, occupancy VGPR-bound
#define G1_ROWS 128
#define XS_STRIDE 17         // scalar stride: xs k-loop reads conflict-free (banks rg*4+k)
// LESSON (r6): no xor-swizzle -- read addresses are positions (swizzle-invariant).
// LESSON (r7): whole-W1-in-LDS (64KB) caps occupancy at 2 blocks/CU (15%) -- stage per-K tile.
// LESSON (r4): wave-per-node x 25k waves >> block-per-bucket x 391 blocks (TLP hides latency).

// ---- workspace layout (float offsets); h1/h2 are PACKED BF16 (uint = 2 ch) ----
#define OFF_H1    0            // h1b: 3.2M uints; reused: h2b=[0,1.6M) uints, out2=[3.2M,6.4M) f32
#define OFF_OUT1  6400000      // f32
#define OFF_ALS1  12800000
#define OFF_ALD1  13600000
#define OFF_ALS2  14400000
#define OFF_ALD2  14500000
#define OFF_BCUR  14600000     // 391 ints (pad to 1024)
#define OFF_ROWP  14601024
#define OFF_CNT   14701024
#define OFF_BIN   14801024     // 391*5120 ints (packed dl<<20|src)
#define OFF_CSR   16802944     // 391*5120 ints (dst-sorted src)

__device__ __forceinline__ float lrelu(float x) { return x >= 0.f ? x : NEG_SLOPE * x; }

__device__ __forceinline__ unsigned f32_to_bf16_rne(float f) {
    unsigned u = __float_as_uint(f);
    return (u + 0x7fffu + ((u >> 16) & 1u)) >> 16;
}
__device__ __forceinline__ unsigned pack_bf16x2(float lo, float hi) {
    return f32_to_bf16_rne(lo) | (f32_to_bf16_rne(hi) << 16);
}
__device__ __forceinline__ float2 unpack_bf16x2(unsigned v) {
    return make_float2(__uint_as_float(v << 16), __uint_as_float(v & 0xffff0000u));
}

__device__ __forceinline__ void edge_src_dst(const int* __restrict__ ei, int e, int& src, int& dst) {
    if (e < NUM_EDGES) { src = ei[e]; dst = ei[NUM_EDGES + e]; }
    else { src = e - NUM_EDGES; dst = e - NUM_EDGES; }
}

// ---------------- K1: h1 = x @ W1 (bf16-packed out), fused f32 logit dots ----------------
__global__ __launch_bounds__(256) void gemm1_kernel(const float* __restrict__ x,
                                                    const float* __restrict__ W1,
                                                    const float* __restrict__ a_src,
                                                    const float* __restrict__ a_dst,
                                                    unsigned* __restrict__ h1b,
                                                    float* __restrict__ als,
                                                    float* __restrict__ ald) {
    __shared__ float wt[16 * D1];               // 4 KB: current K-tile of W1
    __shared__ float xs[G1_ROWS * XS_STRIDE];   // 8.5 KB
    const int tid = threadIdx.x;
    const int rg = tid >> 3;        // 0..31, owns rows rg*4..rg*4+3
    const int cg = tid & 7;         // head cg, cols cg*8..cg*8+7
    const int rg4 = rg * 4;
    const int r0 = blockIdx.x * G1_ROWS;
    const int rr0 = tid >> 2, kk = (tid & 3) * 4, rr1 = rr0 + 64;  // x staging map
    const int wr = tid >> 4, wc = (tid & 15) * 4;                  // W staging map

    float acc[4][8];
#pragma unroll
    for (int j = 0; j < 4; j++)
#pragma unroll
        for (int c = 0; c < 8; c++) acc[j][c] = 0.f;

    for (int kb = 0; kb < NFEAT; kb += 16) {
        float4 xv0 = make_float4(0.f, 0.f, 0.f, 0.f), xv1 = xv0;
        if (r0 + rr0 < N_NODES) xv0 = *(const float4*)&x[(size_t)(r0 + rr0) * NFEAT + kb + kk];
        if (r0 + rr1 < N_NODES) xv1 = *(const float4*)&x[(size_t)(r0 + rr1) * NFEAT + kb + kk];
        const float4 wv4 = *(const float4*)&W1[(size_t)(kb + wr) * D1 + wc];
        __syncthreads();
        xs[rr0 * XS_STRIDE + kk + 0] = xv0.x; xs[rr0 * XS_STRIDE + kk + 1] = xv0.y;
        xs[rr0 * XS_STRIDE + kk + 2] = xv0.z; xs[rr0 * XS_STRIDE + kk + 3] = xv0.w;
        xs[rr1 * XS_STRIDE + kk + 0] = xv1.x; xs[rr1 * XS_STRIDE + kk + 1] = xv1.y;
        xs[rr1 * XS_STRIDE + kk + 2] = xv1.z; xs[rr1 * XS_STRIDE + kk + 3] = xv1.w;
        *(float4*)&wt[wr * D1 + wc] = wv4;
        __syncthreads();
#pragma unroll
        for (int k = 0; k < 16; k++) {
            const float xa[4] = {xs[(rg4 + 0) * XS_STRIDE + k], xs[(rg4 + 1) * XS_STRIDE + k],
                                 xs[(rg4 + 2) * XS_STRIDE + k], xs[(rg4 + 3) * XS_STRIDE + k]};
            const float4 wa = *(const float4*)&wt[k * D1 + cg * 8];
            const float4 wb = *(const float4*)&wt[k * D1 + cg * 8 + 4];
            const float wv[8] = {wa.x, wa.y, wa.z, wa.w, wb.x, wb.y, wb.z, wb.w};
#pragma unroll
            for (int j = 0; j < 4; j++)
#pragma unroll
                for (int c = 0; c < 8; c++) acc[j][c] = fmaf(xa[j], wv[c], acc[j][c]);
        }
    }
    // epilogue: thread owns head cg completely for its 4 rows; logits in f32, h1 bf16-packed
    float asv[8], adv[8];
#pragma unroll
    for (int c = 0; c < 8; c++) { asv[c] = a_src[cg * 8 + c]; adv[c] = a_dst[cg * 8 + c]; }
#pragma unroll
    for (int j = 0; j < 4; j++) {
        const int row = r0 + rg4 + j;
        if (row < N_NODES) {
            uint4 pv;
            pv.x = pack_bf16x2(acc[j][0], acc[j][1]);
            pv.y = pack_bf16x2(acc[j][2], acc[j][3]);
            pv.z = pack_bf16x2(acc[j][4], acc[j][5]);
            pv.w = pack_bf16x2(acc[j][6], acc[j][7]);
            *(uint4*)&h1b[(size_t)row * 32 + cg * 4] = pv;
            float s = 0.f, d = 0.f;
#pragma unroll
            for (int c = 0; c < 8; c++) { s += acc[j][c] * asv[c]; d += acc[j][c] * adv[c]; }
            als[row * HEADS + cg] = s;
            ald[row * HEADS + cg] = d;
        }
    }
}

// ---------------- K2: bin edges by dst bucket (LDS hist + chunk reservation) ----------------
// packed entry: (dst&255)<<20 | src   (src < 2^17)
__global__ __launch_bounds__(256) void bin_kernel(const int* __restrict__ ei,
                                                  int* __restrict__ bcur,
                                                  int* __restrict__ bin) {
    __shared__ int lcnt[NBUCK];
    __shared__ int lbase[NBUCK];
    const int tid = threadIdx.x;
    for (int b = tid; b < NBUCK; b += 256) lcnt[b] = 0;
    __syncthreads();
    const int e0 = blockIdx.x * BIN_EPB;
    int pk[BIN_EPT], bk[BIN_EPT], loff[BIN_EPT];
#pragma unroll
    for (int i = 0; i < BIN_EPT; i++) {
        const int e = e0 + i * 256 + tid;
        if (e < E_TOT) {
            int src, dst; edge_src_dst(ei, e, src, dst);
            bk[i] = dst >> BSHIFT;
            pk[i] = ((dst & 255) << 20) | src;
            loff[i] = atomicAdd(&lcnt[bk[i]], 1);
        } else bk[i] = -1;
    }
    __syncthreads();
    for (int b = tid; b < NBUCK; b += 256) {
        const int c = lcnt[b];
        lbase[b] = c ? atomicAdd(&bcur[b], c) : 0;
    }
    __syncthreads();
#pragma unroll
    for (int i = 0; i < BIN_EPT; i++) {
        if (bk[i] >= 0)
            bin[(size_t)bk[i] * BCAP + lbase[bk[i]] + loff[i]] = pk[i];
    }
}

// ---------------- K3: per-bucket LDS counting sort -> dst-sorted CSR ----------------
__global__ __launch_bounds__(256) void bsort_kernel(const int* __restrict__ bcur,
                                                    const int* __restrict__ bin,
                                                    int* __restrict__ csr,
                                                    int* __restrict__ row_ptr,
                                                    int* __restrict__ cnt) {
    __shared__ int hcnt[256];
    __shared__ int hpre[256];
    __shared__ int cur[256];
    __shared__ int ssrc[BCAP];   // 20 KB
    const int tid = threadIdx.x;
    const int bkt = blockIdx.x;
    const int cntb = bcur[bkt];
    const int base = bkt * BCAP;
    hcnt[tid] = 0;
    __syncthreads();
    for (int i = tid; i < cntb; i += 256)
        atomicAdd(&hcnt[bin[base + i] >> 20], 1);
    __syncthreads();
    const int myc = hcnt[tid];
    hpre[tid] = myc;
    __syncthreads();
    for (int off = 1; off < 256; off <<= 1) {
        const int t = (tid >= off) ? hpre[tid - off] : 0;
        __syncthreads();
        hpre[tid] += t;
        __syncthreads();
    }
    const int exc = hpre[tid] - myc;
    cur[tid] = exc;
    __syncthreads();
    for (int i = tid; i < cntb; i += 256) {
        const int v = bin[base + i];
        const int pos = atomicAdd(&cur[v >> 20], 1);
        ssrc[pos] = v & 0xFFFFF;
    }
    __syncthreads();
    for (int i = tid; i < cntb; i += 256) csr[base + i] = ssrc[i];
    const int n = (bkt << BSHIFT) + tid;
    if (n < N_NODES) { row_ptr[n] = base + exc; cnt[n] = myc; }
}

// ---------------- K4: gather layer 1 -- wave/node, 32 lanes x bf16x2, 2 edge-slots ----------
__global__ __launch_bounds__(256) void gather1_kernel(const int* __restrict__ row_ptr,
                                                      const int* __restrict__ cnt,
                                                      const int* __restrict__ csr_src,
                                                      const unsigned* __restrict__ h1b,
                                                      const float* __restrict__ als,
                                                      const float* __restrict__ ald,
                                                      float* __restrict__ out1) {
    const int tid = threadIdx.x;
    const int n = blockIdx.x * 4 + (tid >> 6);   // grid == N_NODES/4 exactly
    const int l = tid & 63;
    const int half = l >> 5;                     // edge slot 0/1
    const int c2 = l & 31;                       // channels 2c2, 2c2+1
    const int h = c2 >> 2;                       // head (both channels in same head)
    const int start = row_ptr[n];
    const int deg = cnt[n];
    const float aldn = ald[n * HEADS + h];
    float ax = 0.f, ay = 0.f, wsum = 0.f;
    int snext = (half < deg) ? csr_src[start + half] : 0;
    for (int i = half; i < deg; i += 2) {
        const int s = snext;
        if (i + 2 < deg) snext = csr_src[start + i + 2];
        const float w = __expf(lrelu(als[s * HEADS + h] + aldn));
        const float2 hv = unpack_bf16x2(h1b[(size_t)s * 32 + c2]);
        ax = fmaf(hv.x, w, ax);
        ay = fmaf(hv.y, w, ay);
        wsum += w;
    }
    ax += __shfl_down(ax, 32, 64);
    ay += __shfl_down(ay, 32, 64);
    wsum += __shfl_down(wsum, 32, 64);
    if (half == 0) {
        const float inv = 1.f / (wsum + 1e-16f);
        *(float2*)&out1[(size_t)n * D1 + 2 * c2] = make_float2(ax * inv, ay * inv);
    }
}

// ---------------- K5: z = elu(out1+b1); h2 = z @ W2 (bf16-packed); layer-2 logits ----------
__global__ __launch_bounds__(256) void layer2_node_kernel(const float* __restrict__ out1,
                                                          const float* __restrict__ b1,
                                                          const float* __restrict__ W2,
                                                          const float* __restrict__ a_src2,
                                                          const float* __restrict__ a_dst2,
                                                          unsigned* __restrict__ h2b,
                                                          float* __restrict__ als2,
                                                          float* __restrict__ ald2) {
    __shared__ float w2l[D1 * NCLASS];   // 8 KB
    __shared__ float b1l[D1];
    __shared__ float a2l[2 * NCLASS];
    const int tid = threadIdx.x;
    for (int i = tid; i < D1 * NCLASS; i += 256) w2l[i] = W2[i];
    if (tid < D1) b1l[tid] = b1[tid];
    if (tid < NCLASS) a2l[tid] = a_src2[tid];
    else if (tid < 2 * NCLASS) a2l[tid] = a_dst2[tid - NCLASS];
    __syncthreads();

    const int n = blockIdx.x * 256 + tid;
    if (n >= N_NODES) return;
    float acc[NCLASS];
#pragma unroll
    for (int c = 0; c < NCLASS; c++) acc[c] = 0.f;
    float as = 0.f, ad = 0.f;
    const float4* rp = (const float4*)&out1[(size_t)n * D1];
#pragma unroll 2
    for (int k4 = 0; k4 < 16; k4++) {
        const float4 v4 = rp[k4];
        const float vv[4] = {v4.x, v4.y, v4.z, v4.w};
#pragma unroll
        for (int j = 0; j < 4; j++) {
            const int k = k4 * 4 + j;
            float z = vv[j] + b1l[k];
            z = z > 0.f ? z : expm1f(z);   // jax.nn.elu
            const float* wr = &w2l[k * NCLASS];
#pragma unroll
            for (int c = 0; c < NCLASS; c++) acc[c] += z * wr[c];
        }
    }
#pragma unroll
    for (int c = 0; c < NCLASS; c++) { as += acc[c] * a2l[c]; ad += acc[c] * a2l[NCLASS + c]; }
#pragma unroll
    for (int q = 0; q < 4; q++) {
        uint4 pv;
        pv.x = pack_bf16x2(acc[q * 8 + 0], acc[q * 8 + 1]);
        pv.y = pack_bf16x2(acc[q * 8 + 2], acc[q * 8 + 3]);
        pv.z = pack_bf16x2(acc[q * 8 + 4], acc[q * 8 + 5]);
        pv.w = pack_bf16x2(acc[q * 8 + 6], acc[q * 8 + 7]);
        *(uint4*)&h2b[(size_t)n * 16 + q * 4] = pv;
    }
    als2[n] = as; ald2[n] = ad;
}

// ---------------- K6: gather layer 2 -- wave/node, 16 lanes x bf16x2, 4 edge-slots ----------
__global__ __launch_bounds__(256) void gather2_kernel(const int* __restrict__ row_ptr,
                                                      const int* __restrict__ cnt,
                                                      const int* __restrict__ csr_src,
                                                      const unsigned* __restrict__ h2b,
                                                      const float* __restrict__ als2,
                                                      const float* __restrict__ ald2,
                                                      float* __restrict__ out2) {
    const int tid = threadIdx.x;
    const int n = blockIdx.x * 4 + (tid >> 6);   // grid == N_NODES/4 exactly
    const int l = tid & 63;
    const int q = l >> 4;                        // edge slot 0..3
    const int c2 = l & 15;                       // channels 2c2, 2c2+1
    const int start = row_ptr[n];
    const int deg = cnt[n];
    const float aldn = ald2[n];
    float ax = 0.f, ay = 0.f, wsum = 0.f;
    int snext = (q < deg) ? csr_src[start + q] : 0;
    for (int i = q; i < deg; i += 4) {
        const int s = snext;
        if (i + 4 < deg) snext = csr_src[start + i + 4];
        const float w = __expf(lrelu(als2[s] + aldn));
        const float2 hv = unpack_bf16x2(h2b[(size_t)s * 16 + c2]);
        ax = fmaf(hv.x, w, ax);
        ay = fmaf(hv.y, w, ay);
        wsum += w;
    }
    ax += __shfl_down(ax, 32, 64);
    ay += __shfl_down(ay, 32, 64);
    wsum += __shfl_down(wsum, 32, 64);
    ax += __shfl_down(ax, 16, 64);
    ay += __shfl_down(ay, 16, 64);
    wsum += __shfl_down(wsum, 16, 64);
    if (q == 0) {
        const float inv = 1.f / (wsum + 1e-16f);
        *(float2*)&out2[(size_t)n * NCLASS + 2 * c2] = make_float2(ax * inv, ay * inv);
    }
}

// ---------------- K7: + b2, log_softmax ----------------
__global__ __launch_bounds__(256) void logsoftmax_kernel(const float* __restrict__ out2,
                                                         const float* __restrict__ b2,
                                                         float* __restrict__ out) {
    __shared__ float b2l[NCLASS];
    if (threadIdx.x < NCLASS) b2l[threadIdx.x] = b2[threadIdx.x];
    __syncthreads();
    const int n = blockIdx.x * 256 + threadIdx.x;
    if (n >= N_NODES) return;
    float v[NCLASS];
    float mx = -INFINITY;
    const float4* rp = (const float4*)&out2[(size_t)n * NCLASS];
#pragma unroll
    for (int c4 = 0; c4 < NCLASS / 4; c4++) {
        const float4 t = rp[c4];
        v[c4 * 4 + 0] = t.x + b2l[c4 * 4 + 0];
        v[c4 * 4 + 1] = t.y + b2l[c4 * 4 + 1];
        v[c4 * 4 + 2] = t.z + b2l[c4 * 4 + 2];
        v[c4 * 4 + 3] = t.w + b2l[c4 * 4 + 3];
    }
#pragma unroll
    for (int c = 0; c < NCLASS; c++) mx = fmaxf(mx, v[c]);
    float s = 0.f;
#pragma unroll
    for (int c = 0; c < NCLASS; c++) s += __expf(v[c] - mx);
    const float lse = mx + logf(s);
    float4* op = (float4*)&out[(size_t)n * NCLASS];
#pragma unroll
    for (int c4 = 0; c4 < NCLASS / 4; c4++)
        op[c4] = make_float4(v[c4 * 4] - lse, v[c4 * 4 + 1] - lse, v[c4 * 4 + 2] - lse, v[c4 * 4 + 3] - lse);
}

extern "C" void kernel_launch(void* const* d_in, const int* in_sizes, int n_in,
                              void* d_out, int out_size, void* d_ws, size_t ws_size,
                              hipStream_t stream) {
    const float* x      = (const float*)d_in[0];
    const int*   ei     = (const int*)d_in[1];
    const float* W1     = (const float*)d_in[2];
    const float* a_src1 = (const float*)d_in[3];
    const float* a_dst1 = (const float*)d_in[4];
    const float* b1     = (const float*)d_in[5];
    const float* W2     = (const float*)d_in[6];
    const float* a_src2 = (const float*)d_in[7];
    const float* a_dst2 = (const float*)d_in[8];
    const float* b2     = (const float*)d_in[9];
    float* out = (float*)d_out;
    float* ws  = (float*)d_ws;

    unsigned* h1b   = (unsigned*)(ws + OFF_H1);
    float* out1     = ws + OFF_OUT1;
    float* als1     = ws + OFF_ALS1;
    float* ald1     = ws + OFF_ALD1;
    float* als2     = ws + OFF_ALS2;
    float* ald2     = ws + OFF_ALD2;
    int*   bcur     = (int*)(ws + OFF_BCUR);
    int*   row_ptr  = (int*)(ws + OFF_ROWP);
    int*   cnt      = (int*)(ws + OFF_CNT);
    int*   bin      = (int*)(ws + OFF_BIN);
    int*   csr      = (int*)(ws + OFF_CSR);
    unsigned* h2b   = (unsigned*)(ws + OFF_H1);          // alias: h1b dead after gather1
    float* out2     = ws + OFF_H1 + 3200000;             // beyond h2b's 1.6M uints

    hipMemsetAsync(bcur, 0, NBUCK * sizeof(int), stream);

    const int NB = (N_NODES + 255) / 256;   // 391

    gemm1_kernel<<<(N_NODES + G1_ROWS - 1) / G1_ROWS, 256, 0, stream>>>(x, W1, a_src1, a_dst1,
                                                                        h1b, als1, ald1);
    bin_kernel<<<(E_TOT + BIN_EPB - 1) / BIN_EPB, 256, 0, stream>>>(ei, bcur, bin);
    bsort_kernel<<<NBUCK, 256, 0, stream>>>(bcur, bin, csr, row_ptr, cnt);
    gather1_kernel<<<N_NODES / 4, 256, 0, stream>>>(row_ptr, cnt, csr, h1b, als1, ald1, out1);
    layer2_node_kernel<<<NB, 256, 0, stream>>>(out1, b1, W2, a_src2, a_dst2, h2b, als2, ald2);
    gather2_kernel<<<N_NODES / 4, 256, 0, stream>>>(row_ptr, cnt, csr, h2b, als2, ald2, out2);
    logsoftmax_kernel<<<NB, 256, 0, stream>>>(out2, b2, out);
}

// Round 9
// 390.456 us; speedup vs baseline: 3.8653x; 1.0728x over previous
//
#include <hip/hip_runtime.h>
#include <math.h>

#define N_NODES 100000
#define NFEAT 256
#define D1 64          // HEADS*NHID
#define HEADS 8
#define NHID 8
#define NCLASS 32
#define NUM_EDGES 1600000
#define E_TOT 1700000  // + self loops
#define NEG_SLOPE 0.2f

// dst-bucketing: 256 nodes per bucket; CSR stored bucket-strided (no compaction)
#define BSHIFT 8
#define NBUCK 391            // ceil(100000/256)
#define BCAP 5120            // mean edges/bucket 4352, std ~66; +11.6 sigma headroom
#define BIN_EPB 4096
#define BIN_EPT 16

// LESSON (r8): gemm1's limiter was grid size (782 blocks = 3/CU), not LDS; f32 vector
// GEMM caps at ~2x current. MFMA (bf16 in, f32 acc) moves the FLOPs to the matrix pipe
// and leaves only the 102MB x-read as the floor (~17us).
// LESSON (r4): wave-per-node x 25k waves >> block-per-bucket (TLP hides gather latency).

// ---- workspace layout (float offsets); h1/h2 are PACKED BF16 (uint = 2 ch) ----
#define OFF_H1    0            // h1b: 3.2M uints; reused: h2b=[0,1.6M) uints, out2=[3.2M,6.4M) f32
#define OFF_OUT1  6400000      // f32
#define OFF_ALS1  12800000
#define OFF_ALD1  13600000
#define OFF_ALS2  14400000
#define OFF_ALD2  14500000
#define OFF_BCUR  14600000     // 391 ints (pad to 1024)
#define OFF_ROWP  14601024
#define OFF_CNT   14701024
#define OFF_BIN   14801024     // 391*5120 ints (packed dl<<20|src)
#define OFF_CSR   16802944     // 391*5120 ints (dst-sorted src)

typedef __attribute__((ext_vector_type(8))) short bf16x8;
typedef __attribute__((ext_vector_type(4))) float f32x4;

__device__ __forceinline__ float lrelu(float x) { return x >= 0.f ? x : NEG_SLOPE * x; }

__device__ __forceinline__ unsigned f32_to_bf16_rne(float f) {
    unsigned u = __float_as_uint(f);
    return (u + 0x7fffu + ((u >> 16) & 1u)) >> 16;
}
__device__ __forceinline__ unsigned pack_bf16x2(float lo, float hi) {
    return f32_to_bf16_rne(lo) | (f32_to_bf16_rne(hi) << 16);
}
__device__ __forceinline__ float2 unpack_bf16x2(unsigned v) {
    return make_float2(__uint_as_float(v << 16), __uint_as_float(v & 0xffff0000u));
}

__device__ __forceinline__ void edge_src_dst(const int* __restrict__ ei, int e, int& src, int& dst) {
    if (e < NUM_EDGES) { src = ei[e]; dst = ei[NUM_EDGES + e]; }
    else { src = e - NUM_EDGES; dst = e - NUM_EDGES; }
}

// ---------------- K1: h1 = x @ W1 via MFMA 16x16x32 bf16; fused logit dots ----------------
// Block: 64 rows x 64 cols, 4 waves; wave w = col-tile (cols w*16..+15 = heads 2w,2w+1).
// Fragment maps (HW-verified in guide): A[m=lane&15][k=quad*8+j], B[k=quad*8+j][n=lane&15],
// C/D col=lane&15, row=quad*4+reg.
__global__ __launch_bounds__(256) void gemm1_kernel(const float* __restrict__ x,
                                                    const float* __restrict__ W1,
                                                    const float* __restrict__ a_src,
                                                    const float* __restrict__ a_dst,
                                                    ushort* __restrict__ h1u,
                                                    float* __restrict__ als,
                                                    float* __restrict__ ald) {
    __shared__ unsigned xbf[64 * 20];   // 64 rows x 32 bf16, stride 20 uints (5 KB, <=2-way banks)
    const int tid = threadIdx.x;
    const int wv = tid >> 6;            // wave = col-tile
    const int l = tid & 63;
    const int lm = l & 15;
    const int quad = l >> 4;
    const int r0 = blockIdx.x * 64;

    // B-fragments: this wave's 16-col slice of W1, all 8 K-chunks, in registers (32 VGPRs)
    bf16x8 bfrag[8];
#pragma unroll
    for (int kb = 0; kb < 8; kb++)
#pragma unroll
        for (int j = 0; j < 8; j++) {
            const int k = kb * 32 + quad * 8 + j;
            bfrag[kb][j] = (short)f32_to_bf16_rne(W1[k * D1 + wv * 16 + lm]);
        }

    f32x4 acc[4];
#pragma unroll
    for (int s = 0; s < 4; s++) acc[s] = (f32x4)(0.f);

    const int sr = tid >> 2;            // staging: row 0..63
    const int sk = (tid & 3) * 8;       // k-offset within 32-chunk
    const bool rok = (r0 + sr) < N_NODES;
    const float* xrow = &x[(size_t)(r0 + sr) * NFEAT];

    for (int kb = 0; kb < 8; kb++) {
        uint4 pv = make_uint4(0, 0, 0, 0);
        if (rok) {
            const float4 va = *(const float4*)&xrow[kb * 32 + sk];
            const float4 vb = *(const float4*)&xrow[kb * 32 + sk + 4];
            pv.x = pack_bf16x2(va.x, va.y);
            pv.y = pack_bf16x2(va.z, va.w);
            pv.z = pack_bf16x2(vb.x, vb.y);
            pv.w = pack_bf16x2(vb.z, vb.w);
        }
        __syncthreads();   // protect previous chunk's A-frag reads
        *(uint4*)&xbf[sr * 20 + (tid & 3) * 4] = pv;
        __syncthreads();
#pragma unroll
        for (int s = 0; s < 4; s++) {
            const uint4 u = *(const uint4*)&xbf[(s * 16 + lm) * 20 + quad * 4];
            const bf16x8 af = *(const bf16x8*)&u;
            acc[s] = __builtin_amdgcn_mfma_f32_16x16x32_bf16(af, bfrag[kb], acc[s], 0, 0, 0);
        }
    }

    // epilogue: bf16 h1 stores + f32 logit dots (shfl over 8-lane head groups)
    const int head = wv * 2 + (lm >> 3);
    const int jc = l & 7;
    const float asl = a_src[head * NHID + jc];
    const float adl = a_dst[head * NHID + jc];
    const int col = wv * 16 + lm;
#pragma unroll
    for (int s = 0; s < 4; s++) {
#pragma unroll
        for (int r = 0; r < 4; r++) {
            const int row = r0 + s * 16 + quad * 4 + r;
            const float v = acc[s][r];
            float ps = v * asl, pd = v * adl;
            ps += __shfl_xor(ps, 1, 64); pd += __shfl_xor(pd, 1, 64);
            ps += __shfl_xor(ps, 2, 64); pd += __shfl_xor(pd, 2, 64);
            ps += __shfl_xor(ps, 4, 64); pd += __shfl_xor(pd, 4, 64);
            if (row < N_NODES) {
                h1u[(size_t)row * D1 + col] = (ushort)f32_to_bf16_rne(v);
                if (jc == 0) { als[row * HEADS + head] = ps; ald[row * HEADS + head] = pd; }
            }
        }
    }
}

// ---------------- K2: bin edges by dst bucket (LDS hist + chunk reservation) ----------------
// packed entry: (dst&255)<<20 | src   (src < 2^17)
__global__ __launch_bounds__(256) void bin_kernel(const int* __restrict__ ei,
                                                  int* __restrict__ bcur,
                                                  int* __restrict__ bin) {
    __shared__ int lcnt[NBUCK];
    __shared__ int lbase[NBUCK];
    const int tid = threadIdx.x;
    for (int b = tid; b < NBUCK; b += 256) lcnt[b] = 0;
    __syncthreads();
    const int e0 = blockIdx.x * BIN_EPB;
    int pk[BIN_EPT], bk[BIN_EPT], loff[BIN_EPT];
#pragma unroll
    for (int i = 0; i < BIN_EPT; i++) {
        const int e = e0 + i * 256 + tid;
        if (e < E_TOT) {
            int src, dst; edge_src_dst(ei, e, src, dst);
            bk[i] = dst >> BSHIFT;
            pk[i] = ((dst & 255) << 20) | src;
            loff[i] = atomicAdd(&lcnt[bk[i]], 1);
        } else bk[i] = -1;
    }
    __syncthreads();
    for (int b = tid; b < NBUCK; b += 256) {
        const int c = lcnt[b];
        lbase[b] = c ? atomicAdd(&bcur[b], c) : 0;
    }
    __syncthreads();
#pragma unroll
    for (int i = 0; i < BIN_EPT; i++) {
        if (bk[i] >= 0)
            bin[(size_t)bk[i] * BCAP + lbase[bk[i]] + loff[i]] = pk[i];
    }
}

// ---------------- K3: per-bucket LDS counting sort -> dst-sorted CSR ----------------
__global__ __launch_bounds__(256) void bsort_kernel(const int* __restrict__ bcur,
                                                    const int* __restrict__ bin,
                                                    int* __restrict__ csr,
                                                    int* __restrict__ row_ptr,
                                                    int* __restrict__ cnt) {
    __shared__ int hcnt[256];
    __shared__ int hpre[256];
    __shared__ int cur[256];
    __shared__ int ssrc[BCAP];   // 20 KB
    const int tid = threadIdx.x;
    const int bkt = blockIdx.x;
    const int cntb = bcur[bkt];
    const int base = bkt * BCAP;
    hcnt[tid] = 0;
    __syncthreads();
    for (int i = tid; i < cntb; i += 256)
        atomicAdd(&hcnt[bin[base + i] >> 20], 1);
    __syncthreads();
    const int myc = hcnt[tid];
    hpre[tid] = myc;
    __syncthreads();
    for (int off = 1; off < 256; off <<= 1) {
        const int t = (tid >= off) ? hpre[tid - off] : 0;
        __syncthreads();
        hpre[tid] += t;
        __syncthreads();
    }
    const int exc = hpre[tid] - myc;
    cur[tid] = exc;
    __syncthreads();
    for (int i = tid; i < cntb; i += 256) {
        const int v = bin[base + i];
        const int pos = atomicAdd(&cur[v >> 20], 1);
        ssrc[pos] = v & 0xFFFFF;
    }
    __syncthreads();
    for (int i = tid; i < cntb; i += 256) csr[base + i] = ssrc[i];
    const int n = (bkt << BSHIFT) + tid;
    if (n < N_NODES) { row_ptr[n] = base + exc; cnt[n] = myc; }
}

// ---------------- K4: gather layer 1 -- wave/node, 32 lanes x bf16x2, 2 edge-slots ----------
__global__ __launch_bounds__(256) void gather1_kernel(const int* __restrict__ row_ptr,
                                                      const int* __restrict__ cnt,
                                                      const int* __restrict__ csr_src,
                                                      const unsigned* __restrict__ h1b,
                                                      const float* __restrict__ als,
                                                      const float* __restrict__ ald,
                                                      float* __restrict__ out1) {
    const int tid = threadIdx.x;
    const int n = blockIdx.x * 4 + (tid >> 6);   // grid == N_NODES/4 exactly
    const int l = tid & 63;
    const int half = l >> 5;                     // edge slot 0/1
    const int c2 = l & 31;                       // channels 2c2, 2c2+1
    const int h = c2 >> 2;                       // head (both channels in same head)
    const int start = row_ptr[n];
    const int deg = cnt[n];
    const float aldn = ald[n * HEADS + h];
    float ax = 0.f, ay = 0.f, wsum = 0.f;
    int snext = (half < deg) ? csr_src[start + half] : 0;
    for (int i = half; i < deg; i += 2) {
        const int s = snext;
        if (i + 2 < deg) snext = csr_src[start + i + 2];
        const float w = __expf(lrelu(als[s * HEADS + h] + aldn));
        const float2 hv = unpack_bf16x2(h1b[(size_t)s * 32 + c2]);
        ax = fmaf(hv.x, w, ax);
        ay = fmaf(hv.y, w, ay);
        wsum += w;
    }
    ax += __shfl_down(ax, 32, 64);
    ay += __shfl_down(ay, 32, 64);
    wsum += __shfl_down(wsum, 32, 64);
    if (half == 0) {
        const float inv = 1.f / (wsum + 1e-16f);
        *(float2*)&out1[(size_t)n * D1 + 2 * c2] = make_float2(ax * inv, ay * inv);
    }
}

// ---------------- K5: z = elu(out1+b1); h2 = z @ W2 (bf16-packed); layer-2 logits ----------
__global__ __launch_bounds__(256) void layer2_node_kernel(const float* __restrict__ out1,
                                                          const float* __restrict__ b1,
                                                          const float* __restrict__ W2,
                                                          const float* __restrict__ a_src2,
                                                          const float* __restrict__ a_dst2,
                                                          unsigned* __restrict__ h2b,
                                                          float* __restrict__ als2,
                                                          float* __restrict__ ald2) {
    __shared__ float w2l[D1 * NCLASS];   // 8 KB
    __shared__ float b1l[D1];
    __shared__ float a2l[2 * NCLASS];
    const int tid = threadIdx.x;
    for (int i = tid; i < D1 * NCLASS; i += 256) w2l[i] = W2[i];
    if (tid < D1) b1l[tid] = b1[tid];
    if (tid < NCLASS) a2l[tid] = a_src2[tid];
    else if (tid < 2 * NCLASS) a2l[tid] = a_dst2[tid - NCLASS];
    __syncthreads();

    const int n = blockIdx.x * 256 + tid;
    if (n >= N_NODES) return;
    float acc[NCLASS];
#pragma unroll
    for (int c = 0; c < NCLASS; c++) acc[c] = 0.f;
    float as = 0.f, ad = 0.f;
    const float4* rp = (const float4*)&out1[(size_t)n * D1];
#pragma unroll 2
    for (int k4 = 0; k4 < 16; k4++) {
        const float4 v4 = rp[k4];
        const float vv[4] = {v4.x, v4.y, v4.z, v4.w};
#pragma unroll
        for (int j = 0; j < 4; j++) {
            const int k = k4 * 4 + j;
            float z = vv[j] + b1l[k];
            z = z > 0.f ? z : expm1f(z);   // jax.nn.elu
            const float* wr = &w2l[k * NCLASS];
#pragma unroll
            for (int c = 0; c < NCLASS; c++) acc[c] += z * wr[c];
        }
    }
#pragma unroll
    for (int c = 0; c < NCLASS; c++) { as += acc[c] * a2l[c]; ad += acc[c] * a2l[NCLASS + c]; }
#pragma unroll
    for (int q = 0; q < 4; q++) {
        uint4 pv;
        pv.x = pack_bf16x2(acc[q * 8 + 0], acc[q * 8 + 1]);
        pv.y = pack_bf16x2(acc[q * 8 + 2], acc[q * 8 + 3]);
        pv.z = pack_bf16x2(acc[q * 8 + 4], acc[q * 8 + 5]);
        pv.w = pack_bf16x2(acc[q * 8 + 6], acc[q * 8 + 7]);
        *(uint4*)&h2b[(size_t)n * 16 + q * 4] = pv;
    }
    als2[n] = as; ald2[n] = ad;
}

// ---------------- K6: gather layer 2 -- wave/node, 16 lanes x bf16x2, 4 edge-slots ----------
__global__ __launch_bounds__(256) void gather2_kernel(const int* __restrict__ row_ptr,
                                                      const int* __restrict__ cnt,
                                                      const int* __restrict__ csr_src,
                                                      const unsigned* __restrict__ h2b,
                                                      const float* __restrict__ als2,
                                                      const float* __restrict__ ald2,
                                                      float* __restrict__ out2) {
    const int tid = threadIdx.x;
    const int n = blockIdx.x * 4 + (tid >> 6);   // grid == N_NODES/4 exactly
    const int l = tid & 63;
    const int q = l >> 4;                        // edge slot 0..3
    const int c2 = l & 15;                       // channels 2c2, 2c2+1
    const int start = row_ptr[n];
    const int deg = cnt[n];
    const float aldn = ald2[n];
    float ax = 0.f, ay = 0.f, wsum = 0.f;
    int snext = (q < deg) ? csr_src[start + q] : 0;
    for (int i = q; i < deg; i += 4) {
        const int s = snext;
        if (i + 4 < deg) snext = csr_src[start + i + 4];
        const float w = __expf(lrelu(als2[s] + aldn));
        const float2 hv = unpack_bf16x2(h2b[(size_t)s * 16 + c2]);
        ax = fmaf(hv.x, w, ax);
        ay = fmaf(hv.y, w, ay);
        wsum += w;
    }
    ax += __shfl_down(ax, 32, 64);
    ay += __shfl_down(ay, 32, 64);
    wsum += __shfl_down(wsum, 32, 64);
    ax += __shfl_down(ax, 16, 64);
    ay += __shfl_down(ay, 16, 64);
    wsum += __shfl_down(wsum, 16, 64);
    if (q == 0) {
        const float inv = 1.f / (wsum + 1e-16f);
        *(float2*)&out2[(size_t)n * NCLASS + 2 * c2] = make_float2(ax * inv, ay * inv);
    }
}

// ---------------- K7: + b2, log_softmax ----------------
__global__ __launch_bounds__(256) void logsoftmax_kernel(const float* __restrict__ out2,
                                                         const float* __restrict__ b2,
                                                         float* __restrict__ out) {
    __shared__ float b2l[NCLASS];
    if (threadIdx.x < NCLASS) b2l[threadIdx.x] = b2[threadIdx.x];
    __syncthreads();
    const int n = blockIdx.x * 256 + threadIdx.x;
    if (n >= N_NODES) return;
    float v[NCLASS];
    float mx = -INFINITY;
    const float4* rp = (const float4*)&out2[(size_t)n * NCLASS];
#pragma unroll
    for (int c4 = 0; c4 < NCLASS / 4; c4++) {
        const float4 t = rp[c4];
        v[c4 * 4 + 0] = t.x + b2l[c4 * 4 + 0];
        v[c4 * 4 + 1] = t.y + b2l[c4 * 4 + 1];
        v[c4 * 4 + 2] = t.z + b2l[c4 * 4 + 2];
        v[c4 * 4 + 3] = t.w + b2l[c4 * 4 + 3];
    }
#pragma unroll
    for (int c = 0; c < NCLASS; c++) mx = fmaxf(mx, v[c]);
    float s = 0.f;
#pragma unroll
    for (int c = 0; c < NCLASS; c++) s += __expf(v[c] - mx);
    const float lse = mx + logf(s);
    float4* op = (float4*)&out[(size_t)n * NCLASS];
#pragma unroll
    for (int c4 = 0; c4 < NCLASS / 4; c4++)
        op[c4] = make_float4(v[c4 * 4] - lse, v[c4 * 4 + 1] - lse, v[c4 * 4 + 2] - lse, v[c4 * 4 + 3] - lse);
}

extern "C" void kernel_launch(void* const* d_in, const int* in_sizes, int n_in,
                              void* d_out, int out_size, void* d_ws, size_t ws_size,
                              hipStream_t stream) {
    const float* x      = (const float*)d_in[0];
    const int*   ei     = (const int*)d_in[1];
    const float* W1     = (const float*)d_in[2];
    const float* a_src1 = (const float*)d_in[3];
    const float* a_dst1 = (const float*)d_in[4];
    const float* b1     = (const float*)d_in[5];
    const float* W2     = (const float*)d_in[6];
    const float* a_src2 = (const float*)d_in[7];
    const float* a_dst2 = (const float*)d_in[8];
    const float* b2     = (const float*)d_in[9];
    float* out = (float*)d_out;
    float* ws  = (float*)d_ws;

    ushort* h1u     = (ushort*)(ws + OFF_H1);
    unsigned* h1b   = (unsigned*)(ws + OFF_H1);
    float* out1     = ws + OFF_OUT1;
    float* als1     = ws + OFF_ALS1;
    float* ald1     = ws + OFF_ALD1;
    float* als2     = ws + OFF_ALS2;
    float* ald2     = ws + OFF_ALD2;
    int*   bcur     = (int*)(ws + OFF_BCUR);
    int*   row_ptr  = (int*)(ws + OFF_ROWP);
    int*   cnt      = (int*)(ws + OFF_CNT);
    int*   bin      = (int*)(ws + OFF_BIN);
    int*   csr      = (int*)(ws + OFF_CSR);
    unsigned* h2b   = (unsigned*)(ws + OFF_H1);          // alias: h1b dead after gather1
    float* out2     = ws + OFF_H1 + 3200000;             // beyond h2b's 1.6M uints

    hipMemsetAsync(bcur, 0, NBUCK * sizeof(int), stream);

    const int NB = (N_NODES + 255) / 256;   // 391

    gemm1_kernel<<<(N_NODES + 63) / 64, 256, 0, stream>>>(x, W1, a_src1, a_dst1, h1u, als1, ald1);
    bin_kernel<<<(E_TOT + BIN_EPB - 1) / BIN_EPB, 256, 0, stream>>>(ei, bcur, bin);
    bsort_kernel<<<NBUCK, 256, 0, stream>>>(bcur, bin, csr, row_ptr, cnt);
    gather1_kernel<<<N_NODES / 4, 256, 0, stream>>>(row_ptr, cnt, csr, h1b, als1, ald1, out1);
    layer2_node_kernel<<<NB, 256, 0, stream>>>(out1, b1, W2, a_src2, a_dst2, h2b, als2, ald2);
    gather2_kernel<<<N_NODES / 4, 256, 0, stream>>>(row_ptr, cnt, csr, h2b, als2, ald2, out2);
    logsoftmax_kernel<<<NB, 256, 0, stream>>>(out2, b2, out);
}